// Round 6
// baseline (108.661 us; speedup 1.0000x reference)
//
#include <hip/hip_runtime.h>

#define BATCH   8
#define NODES   8192
#define CH      128            // CH_IN == CH_OUT
#define NEXP    64
#define TN      16             // nodes per GEMM tile (M = 8*16 = 128 rows)
#define MAXP    (NODES + NEXP * TN)   // padded sorted-list capacity = 9216
#define NTILES  (MAXP / TN)           // 576 blocks
#define NSORT   64                    // sorter blocks / slices
#define SLICE   (NODES / NSORT)       // 128 sel elems per slice

typedef __attribute__((ext_vector_type(8))) short bf16x8;  // 8 bf16 = 4 VGPRs
typedef __attribute__((ext_vector_type(4))) float f32x4;

typedef const __attribute__((address_space(1))) unsigned int gu32;  // global
typedef __attribute__((address_space(3))) unsigned int lu32;        // LDS

// fp32 -> bf16 RNE via native cast: compiler fuses pairs into
// v_cvt_pk_bf16_f32 (1 instr / 2 elems; m240: scalar cast beats hand-rolled).
__device__ __forceinline__ bf16x8 cvt8(f32x4 lo, f32x4 hi) {
    bf16x8 r;
    #pragma unroll
    for (int i = 0; i < 4; ++i) {
        r[i]     = (short)__builtin_bit_cast(unsigned short, static_cast<__bf16>(lo[i]));
        r[i + 4] = (short)__builtin_bit_cast(unsigned short, static_cast<__bf16>(hi[i]));
    }
    return r;
}

// ---------------------------------------------------------------------------
// K1 (grid 256): W convert (SWIZZLED layout) + sorted[]/texp[] -1 fill +
// distributed partial histogram (blocks 0..63, one 128-elem slice of sel).
// Swizzle (rule #21): logical 16B chunk (row, chk) stored at
// (row, chk ^ (row&7)); gemm stages linearly via global_load_lds and applies
// the same XOR on ds_read -> 2-way (free) LDS bank access.
// ---------------------------------------------------------------------------
__global__ __launch_bounds__(256)
void prep1_kernel(const int* __restrict__ sel, const float* __restrict__ W,
                  short* __restrict__ Wbf, int* __restrict__ sorted,
                  int* __restrict__ texp, int* __restrict__ gcnt)
{
    const int t   = threadIdx.x;
    const int blk = blockIdx.x;

    // (a) W convert with swizzled chunk placement: 2 iters x 8 floats
    #pragma unroll
    for (int i = 0; i < 2; ++i) {
        const int g8  = blk * 512 + i * 256 + t;   // global 8-elem group id
        const int e   = g8 >> 11;                  // 2048 groups per expert
        const int row = (g8 & 2047) >> 4;          // 16 chunks per 128-row
        const int chk = g8 & 15;
        const float* ws = W + (size_t)g8 * 8;
        f32x4 lo = *reinterpret_cast<const f32x4*>(ws);
        f32x4 hi = *reinterpret_cast<const f32x4*>(ws + 4);
        short* wd = Wbf + ((size_t)e << 14) + row * CH + ((chk ^ (row & 7)) << 3);
        *reinterpret_cast<bf16x8*>(wd) = cvt8(lo, hi);
    }

    // (b) -1 fill: sorted pads/tail + tile->expert table
    {
        const int si = blk * 256 + t;
        if (si < MAXP)   sorted[si] = -1;
        if (si < NTILES) texp[si]   = -1;
    }

    // (c) partial histogram for slice blk
    if (blk < NSORT) {
        __shared__ int hist[NEXP];
        if (t < NEXP) hist[t] = 0;
        __syncthreads();
        if (t < SLICE) atomicAdd(&hist[sel[blk * SLICE + t]], 1);
        __syncthreads();
        if (t < NEXP) gcnt[blk * NEXP + t] = hist[t];
    }
}

// ---------------------------------------------------------------------------
// K2 (grid 64 x 128 thr): padded segment starts from the 64x64 partial-count
// matrix (fully unrolled load burst + shfl_up scan) + own cross-block prefix;
// scatter the 128-node slice. Byproduct: texp[tile] = expert for every tile
// that receives at least one node (pure-pad tiles stay -1).
// ---------------------------------------------------------------------------
__global__ __launch_bounds__(128)
void prep2_kernel(const int* __restrict__ sel, const int* __restrict__ gcnt,
                  int* __restrict__ sorted, int* __restrict__ texp)
{
    const int t   = threadIdx.x;
    const int blk = blockIdx.x;

    __shared__ int cursor[NEXP];

    if (t < NEXP) {                 // wave 0: one expert per lane
        int cnt = 0, own = 0;
        #pragma unroll
        for (int s = 0; s < NSORT; ++s) {   // 64 independent loads, one burst
            int g = gcnt[s * NEXP + t];
            own += (s < blk) ? g : 0;
            cnt += g;
        }
        int p = (cnt + TN - 1) & ~(TN - 1);
        int scan = p;               // inclusive padded scan over 64 experts
        #pragma unroll
        for (int d = 1; d < NEXP; d <<= 1) {
            int v = __shfl_up(scan, d);
            if (t >= d) scan += v;
        }
        cursor[t] = (scan - p) + own;   // segment start + cross-block prefix
    }
    __syncthreads();

    if (t < SLICE) {
        int n = blk * SLICE + t;
        int e = sel[n];
        int pos = atomicAdd(&cursor[e], 1);
        sorted[pos] = n;
        // first occupied slot of a 16-aligned tile labels the tile's expert;
        // segment starts are 16-aligned so every non-empty tile gets exactly
        // one writer (all writers of a segment agree on e).
        if ((pos & (TN - 1)) == 0) texp[pos >> 4] = e;
    }
}

// ---------------------------------------------------------------------------
// K3: grouped GEMM, D = W . x^T. Block = 16 nodes, 256 threads = 4 waves.
// Round 6: front-end chain removed —
//  - e comes from texp[tile] (one broadcast load; no sel read, no s_nodes LDS,
//    no first __syncthreads) -> W DMA issues ~600 cyc earlier, waves don't
//    lockstep at a front barrier.
//  - node ids loaded per-lane straight from sorted (L2-hot, broadcast pairs).
//  - x loads / out stores use nontemporal hints: 67 MB of zero-reuse stream
//    traffic stops evicting the 2 MB Wbf (reused ~9x per expert) from L2.
// ---------------------------------------------------------------------------
__global__ __launch_bounds__(256)
void gemm_kernel(const float* __restrict__ x, const short* __restrict__ Wbf,
                 float* __restrict__ out, const int* __restrict__ sorted,
                 const int* __restrict__ texp)
{
    __shared__ short s_w[CH * CH];           // 32 KB swizzled W tile

    const int tid  = threadIdx.x;
    const int tile = blockIdx.x;

    int e = texp[tile];                      // block-uniform broadcast load
    if (e < 0) return;                       // pure-pad tile
    e = __builtin_amdgcn_readfirstlane(e);

    const int wave = tid >> 6;               // 0..3
    const int lane = tid & 63;
    const int m16  = lane & 15;              // A row (out-ch) / B col (node-row)
    const int quad = lane >> 4;              // k-subblock / D out-ch group

    // (1) W DMA ASAP — depends only on e. Wave w copies its 8 KB quarter.
    {
        const char* gsrc = (const char*)(Wbf + ((size_t)e << 14))
                         + wave * 8192 + lane * 16;
        char* ldst = (char*)s_w + wave * 8192;
        #pragma unroll
        for (int i = 0; i < 8; ++i) {
            __builtin_amdgcn_global_load_lds(
                (gu32*)(gsrc + i * 1024),
                (lu32*)(ldst + i * 1024),
                16, 0, 0);
        }
    }

    // (2) per-lane node ids for this lane's B-operand rows
    int          nodej[2];
    const float* xrow[2];
    #pragma unroll
    for (int jt = 0; jt < 2; ++jt) {
        int j    = wave * 32 + jt * 16 + m16;       // block-local output row
        int node = sorted[tile * TN + (j >> 3)];
        int b    = j & 7;
        nodej[jt] = node;
        int nd   = (node >= 0) ? node : 0;          // safe address for pads
        xrow[jt] = x + ((size_t)(b * NODES + nd)) * CH;
    }

    // (3) issue ALL x loads (nontemporal) — latency hides under W DMA
    f32x4 xl[2][4][2];
    #pragma unroll
    for (int jt = 0; jt < 2; ++jt)
        #pragma unroll
        for (int kk = 0; kk < 4; ++kk) {
            const float* p = xrow[jt] + kk * 32 + quad * 8;
            xl[jt][kk][0] = __builtin_nontemporal_load(
                                reinterpret_cast<const f32x4*>(p));
            xl[jt][kk][1] = __builtin_nontemporal_load(
                                reinterpret_cast<const f32x4*>(p) + 1);
        }

    __syncthreads();   // drains vmcnt(0) (x loads + LDS-DMA) + barrier

    // (4) convert x to bf16 fragments (v_cvt_pk)
    bf16x8 xfrag[2][4];
    #pragma unroll
    for (int jt = 0; jt < 2; ++jt)
        #pragma unroll
        for (int kk = 0; kk < 4; ++kk)
            xfrag[jt][kk] = cvt8(xl[jt][kk][0], xl[jt][kk][1]);

    f32x4 acc[2][8];
    #pragma unroll
    for (int jt = 0; jt < 2; ++jt)
        #pragma unroll
        for (int ct = 0; ct < 8; ++ct)
            acc[jt][ct] = (f32x4){0.f, 0.f, 0.f, 0.f};

    // (5) MFMA loop: B-frags from LDS with matching XOR de-swizzle
    #pragma unroll
    for (int kk = 0; kk < 4; ++kk) {
        #pragma unroll
        for (int ct = 0; ct < 8; ++ct) {
            const int row = ct * 16 + m16;
            const bf16x8 wfrag = *reinterpret_cast<const bf16x8*>(
                s_w + row * CH + (((kk * 4 + quad) ^ (row & 7)) << 3));
            acc[0][ct] = __builtin_amdgcn_mfma_f32_16x16x32_bf16(
                             wfrag, xfrag[0][kk], acc[0][ct], 0, 0, 0);
            acc[1][ct] = __builtin_amdgcn_mfma_f32_16x16x32_bf16(
                             wfrag, xfrag[1][kk], acc[1][ct], 0, 0, 0);
        }
    }

    // D layout: col(lane&15) = node-row j, row(quad*4+reg) = out-ch within ct
    // -> lane's f32x4 = out[j][ct*16 + quad*4 .. +3]: one nt dwordx4 store.
    #pragma unroll
    for (int jt = 0; jt < 2; ++jt) {
        int node = nodej[jt];
        if (node < 0) continue;                     // padded row: drop
        int j = wave * 32 + jt * 16 + m16;
        int b = j & 7;
        float* orow = out + ((size_t)(b * NODES + node)) * CH;
        #pragma unroll
        for (int ct = 0; ct < 8; ++ct)
            __builtin_nontemporal_store(acc[jt][ct],
                reinterpret_cast<f32x4*>(orow + ct * 16 + quad * 4));
    }
}

extern "C" void kernel_launch(void* const* d_in, const int* in_sizes, int n_in,
                              void* d_out, int out_size, void* d_ws, size_t ws_size,
                              hipStream_t stream)
{
    const float* x   = (const float*)d_in[0];
    const int*   sel = (const int*)  d_in[1];
    const float* W   = (const float*)d_in[2];
    float*       out = (float*)d_out;

    short* Wbf    = (short*)d_ws;                             // 2 MiB
    int*   sorted = (int*)((char*)d_ws + (size_t)NEXP * CH * CH * sizeof(short));
    int*   gcnt   = sorted + MAXP;                            // 64x64 partials
    int*   texp   = gcnt + NSORT * NEXP;                      // tile -> expert

    prep1_kernel<<<256, 256, 0, stream>>>(sel, W, Wbf, sorted, texp, gcnt);
    prep2_kernel<<<NSORT, 128, 0, stream>>>(sel, gcnt, sorted, texp);
    gemm_kernel<<<NTILES, 256, 0, stream>>>(x, Wbf, out, sorted, texp);
}

// Round 7
// 104.437 us; speedup vs baseline: 1.0404x; 1.0404x over previous
//
#include <hip/hip_runtime.h>

#define BATCH   8
#define NODES   8192
#define CH      128            // CH_IN == CH_OUT
#define NEXP    64
#define TN      16             // nodes per GEMM tile
#define MAXP    (NODES + NEXP * TN)   // padded sorted-list capacity = 9216
#define NTILES  (MAXP / TN)           // 576 tiles
#define NSORT   64                    // sorter blocks / slices
#define SLICE   (NODES / NSORT)       // 128 sel elems per slice

typedef __attribute__((ext_vector_type(8))) short bf16x8;  // 8 bf16 = 4 VGPRs
typedef __attribute__((ext_vector_type(4))) float f32x4;

typedef const __attribute__((address_space(1))) unsigned int gu32;  // global
typedef __attribute__((address_space(3))) unsigned int lu32;        // LDS

// fp32 -> bf16 RNE via native cast: compiler fuses pairs into
// v_cvt_pk_bf16_f32 (1 instr / 2 elems; m240: scalar cast beats hand-rolled).
__device__ __forceinline__ bf16x8 cvt8(f32x4 lo, f32x4 hi) {
    bf16x8 r;
    #pragma unroll
    for (int i = 0; i < 4; ++i) {
        r[i]     = (short)__builtin_bit_cast(unsigned short, static_cast<__bf16>(lo[i]));
        r[i + 4] = (short)__builtin_bit_cast(unsigned short, static_cast<__bf16>(hi[i]));
    }
    return r;
}

// ---------------------------------------------------------------------------
// K1 (grid 256): W convert (SWIZZLED layout) + sorted[]/texp[] -1 fill +
// distributed partial histogram (blocks 0..63, one 128-elem slice of sel).
// Swizzle (rule #21): logical 16B chunk (row, chk) stored at
// (row, chk ^ (row&7)); gemm stages linearly via global_load_lds and applies
// the same XOR on ds_read -> 2-way (free) LDS bank access.
// ---------------------------------------------------------------------------
__global__ __launch_bounds__(256)
void prep1_kernel(const int* __restrict__ sel, const float* __restrict__ W,
                  short* __restrict__ Wbf, int* __restrict__ sorted,
                  int* __restrict__ texp, int* __restrict__ gcnt)
{
    const int t   = threadIdx.x;
    const int blk = blockIdx.x;

    // (a) W convert with swizzled chunk placement: 2 iters x 8 floats
    #pragma unroll
    for (int i = 0; i < 2; ++i) {
        const int g8  = blk * 512 + i * 256 + t;   // global 8-elem group id
        const int e   = g8 >> 11;                  // 2048 groups per expert
        const int row = (g8 & 2047) >> 4;          // 16 chunks per 128-row
        const int chk = g8 & 15;
        const float* ws = W + (size_t)g8 * 8;
        f32x4 lo = *reinterpret_cast<const f32x4*>(ws);
        f32x4 hi = *reinterpret_cast<const f32x4*>(ws + 4);
        short* wd = Wbf + ((size_t)e << 14) + row * CH + ((chk ^ (row & 7)) << 3);
        *reinterpret_cast<bf16x8*>(wd) = cvt8(lo, hi);
    }

    // (b) -1 fill: sorted pads/tail + tile->expert table
    {
        const int si = blk * 256 + t;
        if (si < MAXP)   sorted[si] = -1;
        if (si < NTILES) texp[si]   = -1;
    }

    // (c) partial histogram for slice blk
    if (blk < NSORT) {
        __shared__ int hist[NEXP];
        if (t < NEXP) hist[t] = 0;
        __syncthreads();
        if (t < SLICE) atomicAdd(&hist[sel[blk * SLICE + t]], 1);
        __syncthreads();
        if (t < NEXP) gcnt[blk * NEXP + t] = hist[t];
    }
}

// ---------------------------------------------------------------------------
// K2 (grid 64 x 128 thr): padded segment starts from the 64x64 partial-count
// matrix (unrolled load burst + shfl_up scan) + own cross-block prefix;
// scatter the 128-node slice. Byproduct: texp[tile] = expert for every tile
// that receives at least one node (pure-pad tiles stay -1).
// ---------------------------------------------------------------------------
__global__ __launch_bounds__(128)
void prep2_kernel(const int* __restrict__ sel, const int* __restrict__ gcnt,
                  int* __restrict__ sorted, int* __restrict__ texp)
{
    const int t   = threadIdx.x;
    const int blk = blockIdx.x;

    __shared__ int cursor[NEXP];

    if (t < NEXP) {                 // wave 0: one expert per lane
        int cnt = 0, own = 0;
        #pragma unroll
        for (int s = 0; s < NSORT; ++s) {   // 64 independent loads, one burst
            int g = gcnt[s * NEXP + t];
            own += (s < blk) ? g : 0;
            cnt += g;
        }
        int p = (cnt + TN - 1) & ~(TN - 1);
        int scan = p;               // inclusive padded scan over 64 experts
        #pragma unroll
        for (int d = 1; d < NEXP; d <<= 1) {
            int v = __shfl_up(scan, d);
            if (t >= d) scan += v;
        }
        cursor[t] = (scan - p) + own;   // segment start + cross-block prefix
    }
    __syncthreads();

    if (t < SLICE) {
        int n = blk * SLICE + t;
        int e = sel[n];
        int pos = atomicAdd(&cursor[e], 1);
        sorted[pos] = n;
        // first occupied slot of a 16-aligned tile labels the tile's expert
        if ((pos & (TN - 1)) == 0) texp[pos >> 4] = e;
    }
}

// ---------------------------------------------------------------------------
// K3: grouped GEMM, D = W . x^T. Round 7:
//  - nt hints REVERTED (round-6 regression: nt broke quad-lane 128B segment
//    merging on the 16B x-gathers).
//  - tile split into TWO half-blocks by batch (bh=0: b 0-3, bh=1: b 4-7):
//    grid 1152, ~120 VGPR, 32KB LDS -> ~4 blocks/CU resident (was 2.25) for
//    2x latency overlap of the one-shot load->barrier->compute->store chain.
//    Cost: W DMA per half (36MB L2 total, ~+1us) — bounded, amortized.
// Block = 64 rows (16 nodes x 4 batches), 256 threads = 4 waves; wave w owns
// rows [w*16, w*16+16) x 128 out-ch. Row j: node = sorted[tile*16 + (j>>2)],
// b = bh*4 + (j&3).
// ---------------------------------------------------------------------------
__global__ __launch_bounds__(256)
void gemm_kernel(const float* __restrict__ x, const short* __restrict__ Wbf,
                 float* __restrict__ out, const int* __restrict__ sorted,
                 const int* __restrict__ texp)
{
    __shared__ short s_w[CH * CH];           // 32 KB swizzled W tile

    const int tid  = threadIdx.x;
    const int tile = blockIdx.x >> 1;
    const int bh   = blockIdx.x & 1;         // batch half

    int e = texp[tile];                      // block-uniform broadcast load
    if (e < 0) return;                       // pure-pad tile
    e = __builtin_amdgcn_readfirstlane(e);

    const int wave = tid >> 6;               // 0..3
    const int lane = tid & 63;
    const int m16  = lane & 15;              // A row (out-ch) / B col (node-row)
    const int quad = lane >> 4;              // k-subblock / D out-ch group

    // (1) W DMA ASAP — depends only on e. Wave w copies its 8 KB quarter.
    {
        const char* gsrc = (const char*)(Wbf + ((size_t)e << 14))
                         + wave * 8192 + lane * 16;
        char* ldst = (char*)s_w + wave * 8192;
        #pragma unroll
        for (int i = 0; i < 8; ++i) {
            __builtin_amdgcn_global_load_lds(
                (gu32*)(gsrc + i * 1024),
                (lu32*)(ldst + i * 1024),
                16, 0, 0);
        }
    }

    // (2) this lane's B-operand row: j in [0,64)
    const int j    = wave * 16 + m16;
    const int node = sorted[tile * TN + (j >> 2)];
    const int b    = bh * 4 + (j & 3);
    const int nd   = (node >= 0) ? node : 0;        // safe address for pads
    const float* xrow = x + ((size_t)(b * NODES + nd)) * CH;

    // (3) issue ALL x loads — latency hides under W DMA
    f32x4 xl[4][2];
    #pragma unroll
    for (int kk = 0; kk < 4; ++kk) {
        const float* p = xrow + kk * 32 + quad * 8;
        xl[kk][0] = *reinterpret_cast<const f32x4*>(p);
        xl[kk][1] = *reinterpret_cast<const f32x4*>(p + 4);
    }

    __syncthreads();   // drains vmcnt(0) (x loads + LDS-DMA) + barrier

    // (4) convert x to bf16 fragments (v_cvt_pk)
    bf16x8 xfrag[4];
    #pragma unroll
    for (int kk = 0; kk < 4; ++kk)
        xfrag[kk] = cvt8(xl[kk][0], xl[kk][1]);

    f32x4 acc[8];
    #pragma unroll
    for (int ct = 0; ct < 8; ++ct) acc[ct] = (f32x4){0.f, 0.f, 0.f, 0.f};

    // (5) MFMA loop: B-frags from LDS with matching XOR de-swizzle
    #pragma unroll
    for (int kk = 0; kk < 4; ++kk) {
        #pragma unroll
        for (int ct = 0; ct < 8; ++ct) {
            const int row = ct * 16 + m16;
            const bf16x8 wfrag = *reinterpret_cast<const bf16x8*>(
                s_w + row * CH + (((kk * 4 + quad) ^ (row & 7)) << 3));
            acc[ct] = __builtin_amdgcn_mfma_f32_16x16x32_bf16(
                          wfrag, xfrag[kk], acc[ct], 0, 0, 0);
        }
    }

    // D layout: col(lane&15) = node-row j (this lane's own row), row = out-ch
    // (quad*4+reg) within ct -> lane's f32x4 = out[j][ct*16+quad*4 .. +3].
    if (node >= 0) {
        float* orow = out + ((size_t)(b * NODES + node)) * CH;
        #pragma unroll
        for (int ct = 0; ct < 8; ++ct)
            *reinterpret_cast<f32x4*>(orow + ct * 16 + quad * 4) = acc[ct];
    }
}

extern "C" void kernel_launch(void* const* d_in, const int* in_sizes, int n_in,
                              void* d_out, int out_size, void* d_ws, size_t ws_size,
                              hipStream_t stream)
{
    const float* x   = (const float*)d_in[0];
    const int*   sel = (const int*)  d_in[1];
    const float* W   = (const float*)d_in[2];
    float*       out = (float*)d_out;

    short* Wbf    = (short*)d_ws;                             // 2 MiB
    int*   sorted = (int*)((char*)d_ws + (size_t)NEXP * CH * CH * sizeof(short));
    int*   gcnt   = sorted + MAXP;                            // 64x64 partials
    int*   texp   = gcnt + NSORT * NEXP;                      // tile -> expert

    prep1_kernel<<<256, 256, 0, stream>>>(sel, W, Wbf, sorted, texp, gcnt);
    prep2_kernel<<<NSORT, 128, 0, stream>>>(sel, gcnt, sorted, texp);
    gemm_kernel<<<NTILES * 2, 256, 0, stream>>>(x, Wbf, out, sorted, texp);
}